// Round 1
// baseline (169.450 us; speedup 1.0000x reference)
//
#include <hip/hip_runtime.h>
#include <math.h>

#define HW 4096          // 64*64
#define NB 8
#define NC 512
#define NCHUNK 8
#define CPERCHUNK 64     // 512/8

// ---------------------------------------------------------------------------
// Kernel 1: partial 1x1 convs over a 64-channel chunk.
// part layout: part[(chunk*2 + tensor)*32768 + b*4096 + hw]   (tensor 0=fm,1=x)
// v2: occupancy fix. Old grid was 256 blocks = 1 wave/SIMD (9% occupancy,
// latency-bound at 1.7 TB/s). Split the tensor axis into blockIdx.z and go
// 2 px/thread (float2): 1024 blocks * 256 thr = 4096 waves = 16 waves/CU.
// Per-pixel FP summation tree is UNCHANGED (64 sequential channels per chunk,
// chunks summed in order in kernel 2) -> bit-exact vs previous absmax=0.0.
// ---------------------------------------------------------------------------
__global__ __launch_bounds__(256) void conv_partial(
    const float* __restrict__ fm, const float* __restrict__ x,
    const float* __restrict__ w1, const float* __restrict__ w2,
    float* __restrict__ part)
{
    const int t      = threadIdx.x;
    const int hw2    = blockIdx.x * 512 + t * 2;   // 2 consecutive pixels
    const int chunk  = blockIdx.y;
    const int bz     = blockIdx.z;                 // b*2 + tensor
    const int b      = bz >> 1;
    const int tensor = bz & 1;
    const int c0     = chunk * CPERCHUNK;

    const float* src = (tensor ? x : fm) + ((size_t)b * NC + c0) * HW + hw2;
    const float* w   = tensor ? w2 : w1;

    float a0 = 0.f, a1 = 0.f;

    #pragma unroll 8
    for (int cc = 0; cc < CPERCHUNK; ++cc) {
        const float2 v = *(const float2*)(src + (size_t)cc * HW);
        const float wv = w[c0 + cc];
        a0 = fmaf(v.x, wv, a0);
        a1 = fmaf(v.y, wv, a1);
    }

    float* p = part + ((size_t)(chunk * 2 + tensor) * NB + b) * HW + hw2;
    *(float2*)p = make_float2(a0, a1);
}

// ---------------------------------------------------------------------------
// Kernel 2: sum the 8 chunk partials, add bias, ReLU.
// i = tensor*32768 + b*4096 + hw ; 65536 threads total.
// ---------------------------------------------------------------------------
__global__ __launch_bounds__(256) void reduce_bias_relu(
    const float* __restrict__ part,
    const float* __restrict__ b1, const float* __restrict__ b2,
    float* __restrict__ recon, float* __restrict__ refmap)
{
    const int i      = blockIdx.x * 256 + threadIdx.x;   // 0..65535
    const int tensor = i >> 15;                           // 0 or 1
    const int bhw    = i & 32767;

    float s = 0.f;
    #pragma unroll
    for (int ch = 0; ch < NCHUNK; ++ch)
        s += part[(size_t)(ch * 2 + tensor) * 32768 + bhw];

    const float bias = (tensor == 0) ? b1[0] : b2[0];
    const float r = fmaxf(s + bias, 0.f);
    if (tensor == 0) recon[bhw]  = r;
    else             refmap[bhw] = r;
}

// ---------------------------------------------------------------------------
// Kernel 3: correlation argmax + gather + fold.
// One wave per patch; 4 waves (4 patches) per block; 2048 blocks = 8 b * 256.
// gg in LDS: 65x65 zero-padded recon, stride 65 (bank = (p+q)%32, conflict-free).
// ---------------------------------------------------------------------------
__global__ __launch_bounds__(256) void correlate_gather(
    const float* __restrict__ recon, const float* __restrict__ refmap,
    float* __restrict__ out)
{
    __shared__ float gg[65 * 65];

    const int b     = blockIdx.x >> 8;          // 256 blocks per batch
    const int pbase = (blockIdx.x & 255) * 4;   // 4 patches per block
    const int t     = threadIdx.x;

    // stage zero-padded recon for this batch into LDS
    const float* rb = recon + (size_t)b * HW;
    for (int i = t; i < 65 * 65; i += 256) {
        const int r = i / 65;
        const int c = i - r * 65;
        gg[i] = (r < 64 && c < 64) ? rb[r * 64 + c] : 0.f;
    }
    __syncthreads();

    const int wave = t >> 6;
    const int lane = t & 63;
    const int l    = pbase + wave;       // patch index in [0,1024)
    const int ph   = l >> 5;
    const int pw   = l & 31;

    // 2x2 kernel from refmap patch l (wave-uniform addresses)
    const float* km = refmap + (size_t)b * HW + (ph * 2) * 64 + pw * 2;
    const float k00 = km[0], k01 = km[1], k10 = km[64], k11 = km[65];

    // lane handles window row p = lane; slide over q, reusing right->left
    const int p = lane;
    const float* row0 = gg + p * 65;
    const float* row1 = row0 + 65;

    float best = -INFINITY;
    int   bpos = 0;
    float a  = row0[0];
    float cv = row1[0];
    #pragma unroll
    for (int q = 0; q < 64; ++q) {
        const float bv = row0[q + 1];
        const float dv = row1[q + 1];
        // term order matches einsum reduction order (c, di, dj)
        float v = k00 * a;
        v = fmaf(k01, bv, v);
        v = fmaf(k10, cv, v);
        v = fmaf(k11, dv, v);
        const int pos = p * 64 + q;
        if (v > best) { best = v; bpos = pos; }   // strict > = first-max-wins within lane
        a  = bv;
        cv = dv;
    }

    // butterfly reduce across 64 lanes: max value, min position on ties
    #pragma unroll
    for (int m = 1; m < 64; m <<= 1) {
        const float ov = __shfl_xor(best, m, 64);
        const int   op = __shfl_xor(bpos, m, 64);
        if (ov > best || (ov == best && op < bpos)) { best = ov; bpos = op; }
    }

    if (lane == 0) {
        const int idx = bpos >> 2;       // offset // 4
        const int ph2 = idx >> 5;
        const int pw2 = idx & 31;
        const float* src = gg + (ph2 * 2) * 65 + pw2 * 2;   // recon patch idx
        float* o = out + (size_t)b * HW + (ph * 2) * 64 + pw * 2;
        o[0]  = src[0];
        o[1]  = src[1];
        o[64] = src[65];
        o[65] = src[66];
    }
}

// ---------------------------------------------------------------------------
extern "C" void kernel_launch(void* const* d_in, const int* in_sizes, int n_in,
                              void* d_out, int out_size, void* d_ws, size_t ws_size,
                              hipStream_t stream)
{
    const float* spade_fm = (const float*)d_in[0];
    const float* x        = (const float*)d_in[1];
    const float* w1       = (const float*)d_in[2];
    const float* b1       = (const float*)d_in[3];
    const float* w2       = (const float*)d_in[4];
    const float* b2       = (const float*)d_in[5];
    float* out = (float*)d_out;

    float* part   = (float*)d_ws;                 // 16 * 32768 floats = 2 MB
    float* recon  = part + 16 * 32768;            // 8*4096 floats
    float* refmap = recon + NB * HW;              // 8*4096 floats

    dim3 g1(8, NCHUNK, NB * 2);                   // 1024 blocks, tensor in z
    conv_partial<<<g1, 256, 0, stream>>>(spade_fm, x, w1, w2, part);
    reduce_bias_relu<<<256, 256, 0, stream>>>(part, b1, b2, recon, refmap);
    correlate_gather<<<2048, 256, 0, stream>>>(recon, refmap, out);
}

// Round 2
// 167.908 us; speedup vs baseline: 1.0092x; 1.0092x over previous
//
#include <hip/hip_runtime.h>
#include <math.h>

#define HW 4096          // 64*64
#define NB 8
#define NC 512
#define NCHUNK 8
#define CPERCHUNK 64     // 512/8

// ---------------------------------------------------------------------------
// Kernel 1: partial 1x1 convs over a 64-channel chunk.
// part layout: part[(chunk*2 + tensor)*32768 + b*4096 + hw]   (tensor 0=fm,1=x)
// v3: memory-level-parallelism fix. v1 (9% occ) and v2 (30% occ) both sat at
// 42 us / 1.6 TB/s HBM -> not wave-count-limited; bytes-in-flight-limited
// (compiler only kept ~4 loads outstanding; VGPR=16 in v2). Force 16
// outstanding float2 loads per thread via a statically-indexed register
// batch: 8 KB/wave in flight * 16 waves/CU ~ 128 KB/CU.
// FMA order per accumulator is still strict channel order cc=0..63 within
// the chunk; chunk partials still summed in order in kernel 2 -> bit-exact.
// ---------------------------------------------------------------------------
__global__ __launch_bounds__(256) void conv_partial(
    const float* __restrict__ fm, const float* __restrict__ x,
    const float* __restrict__ w1, const float* __restrict__ w2,
    float* __restrict__ part)
{
    const int t      = threadIdx.x;
    const int hw2    = blockIdx.x * 512 + t * 2;   // 2 consecutive pixels
    const int chunk  = blockIdx.y;
    const int bz     = blockIdx.z;                 // b*2 + tensor
    const int b      = bz >> 1;
    const int tensor = bz & 1;
    const int c0     = chunk * CPERCHUNK;

    const float* src = (tensor ? x : fm) + ((size_t)b * NC + c0) * HW + hw2;
    const float* w   = tensor ? w2 : w1;

    float a0 = 0.f, a1 = 0.f;

    // 4 batches of 16 channels: issue all 16 loads, then FMA in channel order.
    #pragma unroll
    for (int base = 0; base < CPERCHUNK; base += 16) {
        float2 v[16];
        #pragma unroll
        for (int k = 0; k < 16; ++k)
            v[k] = *(const float2*)(src + (size_t)(base + k) * HW);
        #pragma unroll
        for (int k = 0; k < 16; ++k) {
            const float wv = w[c0 + base + k];
            a0 = fmaf(v[k].x, wv, a0);
            a1 = fmaf(v[k].y, wv, a1);
        }
    }

    float* p = part + ((size_t)(chunk * 2 + tensor) * NB + b) * HW + hw2;
    *(float2*)p = make_float2(a0, a1);
}

// ---------------------------------------------------------------------------
// Kernel 2: sum the 8 chunk partials, add bias, ReLU.
// i = tensor*32768 + b*4096 + hw ; 65536 threads total.
// ---------------------------------------------------------------------------
__global__ __launch_bounds__(256) void reduce_bias_relu(
    const float* __restrict__ part,
    const float* __restrict__ b1, const float* __restrict__ b2,
    float* __restrict__ recon, float* __restrict__ refmap)
{
    const int i      = blockIdx.x * 256 + threadIdx.x;   // 0..65535
    const int tensor = i >> 15;                           // 0 or 1
    const int bhw    = i & 32767;

    float s = 0.f;
    #pragma unroll
    for (int ch = 0; ch < NCHUNK; ++ch)
        s += part[(size_t)(ch * 2 + tensor) * 32768 + bhw];

    const float bias = (tensor == 0) ? b1[0] : b2[0];
    const float r = fmaxf(s + bias, 0.f);
    if (tensor == 0) recon[bhw]  = r;
    else             refmap[bhw] = r;
}

// ---------------------------------------------------------------------------
// Kernel 3: correlation argmax + gather + fold.
// One wave per patch; 4 waves (4 patches) per block; 2048 blocks = 8 b * 256.
// gg in LDS: 65x65 zero-padded recon, stride 65 (bank = (p+q)%32, conflict-free).
// ---------------------------------------------------------------------------
__global__ __launch_bounds__(256) void correlate_gather(
    const float* __restrict__ recon, const float* __restrict__ refmap,
    float* __restrict__ out)
{
    __shared__ float gg[65 * 65];

    const int b     = blockIdx.x >> 8;          // 256 blocks per batch
    const int pbase = (blockIdx.x & 255) * 4;   // 4 patches per block
    const int t     = threadIdx.x;

    // stage zero-padded recon for this batch into LDS
    const float* rb = recon + (size_t)b * HW;
    for (int i = t; i < 65 * 65; i += 256) {
        const int r = i / 65;
        const int c = i - r * 65;
        gg[i] = (r < 64 && c < 64) ? rb[r * 64 + c] : 0.f;
    }
    __syncthreads();

    const int wave = t >> 6;
    const int lane = t & 63;
    const int l    = pbase + wave;       // patch index in [0,1024)
    const int ph   = l >> 5;
    const int pw   = l & 31;

    // 2x2 kernel from refmap patch l (wave-uniform addresses)
    const float* km = refmap + (size_t)b * HW + (ph * 2) * 64 + pw * 2;
    const float k00 = km[0], k01 = km[1], k10 = km[64], k11 = km[65];

    // lane handles window row p = lane; slide over q, reusing right->left
    const int p = lane;
    const float* row0 = gg + p * 65;
    const float* row1 = row0 + 65;

    float best = -INFINITY;
    int   bpos = 0;
    float a  = row0[0];
    float cv = row1[0];
    #pragma unroll
    for (int q = 0; q < 64; ++q) {
        const float bv = row0[q + 1];
        const float dv = row1[q + 1];
        // term order matches einsum reduction order (c, di, dj)
        float v = k00 * a;
        v = fmaf(k01, bv, v);
        v = fmaf(k10, cv, v);
        v = fmaf(k11, dv, v);
        const int pos = p * 64 + q;
        if (v > best) { best = v; bpos = pos; }   // strict > = first-max-wins within lane
        a  = bv;
        cv = dv;
    }

    // butterfly reduce across 64 lanes: max value, min position on ties
    #pragma unroll
    for (int m = 1; m < 64; m <<= 1) {
        const float ov = __shfl_xor(best, m, 64);
        const int   op = __shfl_xor(bpos, m, 64);
        if (ov > best || (ov == best && op < bpos)) { best = ov; bpos = op; }
    }

    if (lane == 0) {
        const int idx = bpos >> 2;       // offset // 4
        const int ph2 = idx >> 5;
        const int pw2 = idx & 31;
        const float* src = gg + (ph2 * 2) * 65 + pw2 * 2;   // recon patch idx
        float* o = out + (size_t)b * HW + (ph * 2) * 64 + pw * 2;
        o[0]  = src[0];
        o[1]  = src[1];
        o[64] = src[65];
        o[65] = src[66];
    }
}

// ---------------------------------------------------------------------------
extern "C" void kernel_launch(void* const* d_in, const int* in_sizes, int n_in,
                              void* d_out, int out_size, void* d_ws, size_t ws_size,
                              hipStream_t stream)
{
    const float* spade_fm = (const float*)d_in[0];
    const float* x        = (const float*)d_in[1];
    const float* w1       = (const float*)d_in[2];
    const float* b1       = (const float*)d_in[3];
    const float* w2       = (const float*)d_in[4];
    const float* b2       = (const float*)d_in[5];
    float* out = (float*)d_out;

    float* part   = (float*)d_ws;                 // 16 * 32768 floats = 2 MB
    float* recon  = part + 16 * 32768;            // 8*4096 floats
    float* refmap = recon + NB * HW;              // 8*4096 floats

    dim3 g1(8, NCHUNK, NB * 2);                   // 1024 blocks, tensor in z
    conv_partial<<<g1, 256, 0, stream>>>(spade_fm, x, w1, w2, part);
    reduce_bias_relu<<<256, 256, 0, stream>>>(part, b1, b2, recon, refmap);
    correlate_gather<<<2048, 256, 0, stream>>>(recon, refmap, out);
}

// Round 3
// 163.811 us; speedup vs baseline: 1.0344x; 1.0250x over previous
//
#include <hip/hip_runtime.h>
#include <math.h>

#define HW 4096          // 64*64
#define NB 8
#define NC 512

// ---------------------------------------------------------------------------
// Kernel 1 (v4): FUSED 1x1 convs + chunk-reduce + bias + ReLU.
//
// History: v1 (256 blk, float4, 4-deep), v2 (1024 blk, float2), v3 (16-deep
// MLP, VGPR=48) ALL measured 42 us / ~3.2 TB/s effective read. Read-path
// ceiling reached (write-only fills hit 6.27 TB/s; copy's 6.29 is read+write
// sum -> pure-read ceiling ~3.2-3.4 TB/s). So: stop tuning the stream, cut
// the remaining fat instead — fuse the old reduce_bias_relu kernel away
// (saves 2 MB part write + 2 MB part read + one launch).
//
// Bit-exactness: per pixel we compute
//   s = 0; for chunk 0..7 { a = fold_{cc=0..63} fma(v,w,a) ; s += a }  (+bias, relu)
// which is EXACTLY the old k1 (per-chunk fold, cc in order) followed by the
// old k2 (left-fold over chunks starting from 0.f). Same FP tree -> same bits.
//
// Grid: (16 x-tiles of 256 px, 16 bz = b*2+tensor) = 256 blocks (v1's proven
// block count). Thread = 1 pixel; loads are 256 B/wave-instr coalesced;
// 32-channel load batches keep 8 KB/wave in flight.
// ---------------------------------------------------------------------------
__global__ __launch_bounds__(256) void conv_reduce(
    const float* __restrict__ fm, const float* __restrict__ x,
    const float* __restrict__ w1, const float* __restrict__ w2,
    const float* __restrict__ b1, const float* __restrict__ b2,
    float* __restrict__ recon, float* __restrict__ refmap)
{
    const int t      = threadIdx.x;
    const int px     = blockIdx.x * 256 + t;       // pixel in [0,4096)
    const int bz     = blockIdx.y;                 // b*2 + tensor
    const int b      = bz >> 1;
    const int tensor = bz & 1;

    const float* src = (tensor ? x : fm) + (size_t)b * NC * HW + px;
    const float* w   = tensor ? w2 : w1;

    float s = 0.f;

    #pragma unroll
    for (int chunk = 0; chunk < 8; ++chunk) {
        float a = 0.f;
        #pragma unroll
        for (int half = 0; half < 2; ++half) {
            const int c0 = chunk * 64 + half * 32;
            float v[32];
            #pragma unroll
            for (int k = 0; k < 32; ++k)
                v[k] = src[(size_t)(c0 + k) * HW];
            #pragma unroll
            for (int k = 0; k < 32; ++k)
                a = fmaf(v[k], w[c0 + k], a);
        }
        s += a;          // chunk-order left fold == old reduce_bias_relu
    }

    const float bias = tensor ? b2[0] : b1[0];
    const float r = fmaxf(s + bias, 0.f);
    if (tensor == 0) recon[b * HW + px]  = r;
    else             refmap[b * HW + px] = r;
}

// ---------------------------------------------------------------------------
// Kernel 3: correlation argmax + gather + fold. (unchanged)
// One wave per patch; 4 waves (4 patches) per block; 2048 blocks = 8 b * 256.
// gg in LDS: 65x65 zero-padded recon, stride 65 (bank = (p+q)%32, conflict-free).
// ---------------------------------------------------------------------------
__global__ __launch_bounds__(256) void correlate_gather(
    const float* __restrict__ recon, const float* __restrict__ refmap,
    float* __restrict__ out)
{
    __shared__ float gg[65 * 65];

    const int b     = blockIdx.x >> 8;          // 256 blocks per batch
    const int pbase = (blockIdx.x & 255) * 4;   // 4 patches per block
    const int t     = threadIdx.x;

    // stage zero-padded recon for this batch into LDS
    const float* rb = recon + (size_t)b * HW;
    for (int i = t; i < 65 * 65; i += 256) {
        const int r = i / 65;
        const int c = i - r * 65;
        gg[i] = (r < 64 && c < 64) ? rb[r * 64 + c] : 0.f;
    }
    __syncthreads();

    const int wave = t >> 6;
    const int lane = t & 63;
    const int l    = pbase + wave;       // patch index in [0,1024)
    const int ph   = l >> 5;
    const int pw   = l & 31;

    // 2x2 kernel from refmap patch l (wave-uniform addresses)
    const float* km = refmap + (size_t)b * HW + (ph * 2) * 64 + pw * 2;
    const float k00 = km[0], k01 = km[1], k10 = km[64], k11 = km[65];

    // lane handles window row p = lane; slide over q, reusing right->left
    const int p = lane;
    const float* row0 = gg + p * 65;
    const float* row1 = row0 + 65;

    float best = -INFINITY;
    int   bpos = 0;
    float a  = row0[0];
    float cv = row1[0];
    #pragma unroll
    for (int q = 0; q < 64; ++q) {
        const float bv = row0[q + 1];
        const float dv = row1[q + 1];
        // term order matches einsum reduction order (c, di, dj)
        float v = k00 * a;
        v = fmaf(k01, bv, v);
        v = fmaf(k10, cv, v);
        v = fmaf(k11, dv, v);
        const int pos = p * 64 + q;
        if (v > best) { best = v; bpos = pos; }   // strict > = first-max-wins within lane
        a  = bv;
        cv = dv;
    }

    // butterfly reduce across 64 lanes: max value, min position on ties
    #pragma unroll
    for (int m = 1; m < 64; m <<= 1) {
        const float ov = __shfl_xor(best, m, 64);
        const int   op = __shfl_xor(bpos, m, 64);
        if (ov > best || (ov == best && op < bpos)) { best = ov; bpos = op; }
    }

    if (lane == 0) {
        const int idx = bpos >> 2;       // offset // 4
        const int ph2 = idx >> 5;
        const int pw2 = idx & 31;
        const float* src = gg + (ph2 * 2) * 65 + pw2 * 2;   // recon patch idx
        float* o = out + (size_t)b * HW + (ph * 2) * 64 + pw * 2;
        o[0]  = src[0];
        o[1]  = src[1];
        o[64] = src[65];
        o[65] = src[66];
    }
}

// ---------------------------------------------------------------------------
extern "C" void kernel_launch(void* const* d_in, const int* in_sizes, int n_in,
                              void* d_out, int out_size, void* d_ws, size_t ws_size,
                              hipStream_t stream)
{
    const float* spade_fm = (const float*)d_in[0];
    const float* x        = (const float*)d_in[1];
    const float* w1       = (const float*)d_in[2];
    const float* b1       = (const float*)d_in[3];
    const float* w2       = (const float*)d_in[4];
    const float* b2       = (const float*)d_in[5];
    float* out = (float*)d_out;

    float* recon  = (float*)d_ws;                 // 8*4096 floats
    float* refmap = recon + NB * HW;              // 8*4096 floats

    dim3 g1(16, 16);                              // 256 blocks
    conv_reduce<<<g1, 256, 0, stream>>>(spade_fm, x, w1, w2, b1, b2, recon, refmap);
    correlate_gather<<<2048, 256, 0, stream>>>(recon, refmap, out);
}